// Round 18
// baseline (566.654 us; speedup 1.0000x reference)
//
#include <hip/hip_runtime.h>

#define NWIN 49
#define CDIM 128
#define SCALEQ 0.17677669529663687f
#define LOG2E  1.4426950408889634f

typedef _Float16 half8 __attribute__((ext_vector_type(8)));
typedef _Float16 half4v __attribute__((ext_vector_type(4)));
typedef float f32x4 __attribute__((ext_vector_type(4)));
typedef float f32x16 __attribute__((ext_vector_type(16)));

// ---- d_ws f16 layout (element offsets) ----
#define WS_WQKV  0        // [384][128] f16, q-rows pre-scaled by SCALEQ*LOG2E
#define WS_WPROJ 49152    // [128][128] f16
#define WS_BQKV  65536    // [384] f16 (q part pre-scaled by SCALEQ*LOG2E)
#define WS_BIAS  65920    // [4][49][64] f16: bias*LOG2E, key>=49 -> -1.44e4
#define WS_TOTAL 78464    // halves

// ---- LDS strides (halves) ----
#define XL_STR 136        // x / O tile row stride (272 B)
#define QK_STR 40         // Q,K row stride (80 B)
#define P_STR  72         // P row stride (144 B); cols 64..67 hold f32 partial sums
#define VT_STR 72         // V[d][token] row stride (144 B; 64 tokens + pad)

#define XBUF_H  (49 * XL_STR)          // 6664 halves: x only
#define K_OFF_H (64 * QK_STR)          // 2560: K after Q
#define HEAD_H  (2 * K_OFF_H)          // 5120 per head (P overlay 64*72=4608 <= 5120)
#define VBUF_H  (32 * VT_STR)          // 2304 per head: V[d][token]
#define VREG_H  (4 * VBUF_H)           // 9216: all-V region; O (64x136=8704) overlays it
#define SMEM_H  (XBUF_H + 4 * HEAD_H + VREG_H) // 36360 halves = 72720 B -> 2 blocks/CU

static __device__ __forceinline__ half4v pk4(float a, float b, float c, float d) {
    auto p0 = __builtin_amdgcn_cvt_pkrtz(a, b);
    auto p1 = __builtin_amdgcn_cvt_pkrtz(c, d);
    int2 r = { __builtin_bit_cast(int, p0), __builtin_bit_cast(int, p1) };
    return __builtin_bit_cast(half4v, r);
}
static __device__ __forceinline__ half8 pk8(float4 u0, float4 u1) {
    auto p0 = __builtin_amdgcn_cvt_pkrtz(u0.x, u0.y);
    auto p1 = __builtin_amdgcn_cvt_pkrtz(u0.z, u0.w);
    auto p2 = __builtin_amdgcn_cvt_pkrtz(u1.x, u1.y);
    auto p3 = __builtin_amdgcn_cvt_pkrtz(u1.z, u1.w);
    int4 r = { __builtin_bit_cast(int, p0), __builtin_bit_cast(int, p1),
               __builtin_bit_cast(int, p2), __builtin_bit_cast(int, p3) };
    return __builtin_bit_cast(half8, r);
}

__global__ __launch_bounds__(256)
void prepack(const float* __restrict__ w_qkv, const float* __restrict__ b_qkv,
             const float* __restrict__ w_proj, const float* __restrict__ bias_table,
             const int* __restrict__ rel_index, _Float16* __restrict__ ws)
{
    int i = blockIdx.x * 256 + threadIdx.x;
    if (i < 49152) {
        float v = w_qkv[i];
        if (i < 16384) v *= SCALEQ * LOG2E;  // q rows: fold softmax base-2
        ws[WS_WQKV + i] = (_Float16)v;
    } else if (i < 65536) {
        ws[i] = (_Float16)w_proj[i - 49152];
    } else if (i < 65920) {
        int n = i - 65536;
        float v = b_qkv[n];
        if (n < 128) v *= SCALEQ * LOG2E;
        ws[WS_BQKV + n] = (_Float16)v;
    } else if (i < WS_TOTAL) {
        int t = i - 65920;
        int h = t / 3136;                    // 49*64
        int r = t - h * 3136;
        int q = r >> 6;
        int key = r & 63;
        float v = (key < 49) ? bias_table[(size_t)rel_index[q * 49 + key] * 4 + h] * LOG2E
                             : -1.44e4f;     // exp2 -> 0
        ws[WS_BIAS + t] = (_Float16)v;
    }
}

// 512 threads = 8 waves. r17 base (299us) + GEMM1 retiled to 32x32x16 MFMA:
// wave (rt = w>>2, ct = w&3) computes head ct's Q,K,V for tokens 32rt..+31 as
// three 32x32 tiles. One x-frag set (8 b128, HALF of r17's 16) serves all
// three as both operands. Q/K swapped (mfma(w,x) -> D[outcol][token] -> packed
// stores into unchanged Q[token][d]); V unswapped -> packed V^T stores. All
// fragment patterns r16-verified via GEMM3. T14 loads moved post-B1 so stage
// regs no longer overlap GEMM1 (r17's +12MB WRITE spill tell).
__global__ __launch_bounds__(512)
void lwa_fused(const float* __restrict__ x, const _Float16* __restrict__ ws,
               const float* __restrict__ b_proj, float* __restrict__ out,
               int nwin_total, int wpb)
{
    __shared__ __align__(16) _Float16 smem[SMEM_H];

    const int tid  = threadIdx.x;
    const int w    = tid >> 6;
    const int h    = w >> 1;
    const int c    = w & 1;
    const int lane = tid & 63;
    const int lo   = lane & 15;
    const int hi   = lane >> 4;

    _Float16* const xb = smem;                       // x (49 x 136)
    _Float16* const Qh = smem + XBUF_H + h * HEAD_H; // 64 x 32, stride 40 (reader view)
    _Float16* const Kh = Qh + K_OFF_H;
    _Float16* const Ph = Qh;                         // overlay: 64 x 64 (+sums pad), stride 72
    _Float16* const Vh = smem + XBUF_H + 4 * HEAD_H + h * VBUF_H; // V[d][token] (reader view)
    _Float16* const Ob = smem + XBUF_H + 4 * HEAD_H; // O (64 x 136) overlays V region

    const f32x4 zf = {0.f, 0.f, 0.f, 0.f};

    // 32x32-tile mapping (GEMM1 + GEMM3): wave (rt, ct), lane (cl, kh)
    const int rt = w >> 2;          // token/row tile 0..1
    const int ct = w & 3;           // head (GEMM1) / col-tile (GEMM3) 0..3
    const int cl = lane & 31;
    const int kh = lane >> 5;
    const float bpe3 = b_proj[32 * ct + cl];

    // GEMM1 writer-view regions (head ct)
    _Float16* const Qr = smem + XBUF_H + ct * HEAD_H;
    _Float16* const Kr = Qr + K_OFF_H;
    _Float16* const Vr = smem + XBUF_H + 4 * HEAD_H + ct * VBUF_H;

    const int r0 = tid >> 4;            // 0..31
    const int gc = (tid & 15) * 8;

    int b0 = blockIdx.x * wpb;
    int b1 = b0 + wpb; if (b1 > nwin_total) b1 = nwin_total;

    // ---------- prologue: stage x[b0] ----------
    {
        const float* xs = x + (size_t)b0 * NWIN * CDIM;
#pragma unroll
        for (int p = 0; p < 2; ++p) {
            int row = r0 + p * 32;
            if (row < 49) {
                const float* sp = xs + (size_t)row * CDIM + gc;
                float4 u0 = *reinterpret_cast<const float4*>(sp);
                float4 u1 = *reinterpret_cast<const float4*>(sp + 4);
                *reinterpret_cast<half8*>(&xb[row * XL_STR + gc]) = pk8(u0, u1);
            }
        }
    }
    __syncthreads();   // B0 (prologue only): x visible

    for (int b = b0; b < b1; ++b) {
        const bool hn = (b + 1 < b1);

        // ---- GEMM1: three 32x32 tiles (q,k,v) for head ct, tokens 32rt..+31 ----
        {
            int tr = 32 * rt + cl; if (tr > 48) tr = 48;   // clamp: pad tokens dup 48
            half8 xf[8];
#pragma unroll
            for (int kk = 0; kk < 8; ++kk)
                xf[kk] = *reinterpret_cast<const half8*>(&xb[tr * XL_STR + kk * 16 + kh * 8]);

#pragma unroll 1
            for (int t = 0; t < 3; ++t) {
                const _Float16* wp = ws + WS_WQKV
                    + ((size_t)(t * CDIM + 32 * ct + cl)) * CDIM + kh * 8;
                half8 wfr[8];
#pragma unroll
                for (int kk = 0; kk < 8; ++kk)
                    wfr[kk] = *reinterpret_cast<const half8*>(wp + kk * 16);

                f32x16 g;
                if (t < 2) {
                    // bias per outcol: D rows = outcol (r&3)+8(r>>2)+4kh
#pragma unroll
                    for (int g2 = 0; g2 < 4; ++g2) {
                        half4v b4 = *reinterpret_cast<const half4v*>(
                            ws + WS_BQKV + t * CDIM + 32 * ct + 8 * g2 + 4 * kh);
#pragma unroll
                        for (int j = 0; j < 4; ++j) g[4 * g2 + j] = (float)b4[j];
                    }
#pragma unroll
                    for (int kk = 0; kk < 8; ++kk)
                        g = __builtin_amdgcn_mfma_f32_32x32x16_f16(wfr[kk], xf[kk], g, 0, 0, 0);
                    // D[outcol][token]: lane token = 32rt+cl, outcols in 4 groups of 4
                    _Float16* dst = (t == 0) ? Qr : Kr;
#pragma unroll
                    for (int g2 = 0; g2 < 4; ++g2)
                        *reinterpret_cast<half4v*>(
                            &dst[(32 * rt + cl) * QK_STR + 8 * g2 + 4 * kh]) =
                            pk4(g[4 * g2], g[4 * g2 + 1], g[4 * g2 + 2], g[4 * g2 + 3]);
                } else {
                    float bv = (float)ws[WS_BQKV + 2 * CDIM + 32 * ct + cl];
#pragma unroll
                    for (int r = 0; r < 16; ++r) g[r] = bv;
#pragma unroll
                    for (int kk = 0; kk < 8; ++kk)
                        g = __builtin_amdgcn_mfma_f32_32x32x16_f16(xf[kk], wfr[kk], g, 0, 0, 0);
                    // D[token][vcol]: lane vcol = cl, tokens in 4 groups of 4
#pragma unroll
                    for (int g2 = 0; g2 < 4; ++g2)
                        *reinterpret_cast<half4v*>(
                            &Vr[cl * VT_STR + 32 * rt + 8 * g2 + 4 * kh]) =
                            pk4(g[4 * g2], g[4 * g2 + 1], g[4 * g2 + 2], g[4 * g2 + 3]);
                }
            }
        }
        __syncthreads();  // B1: Q,K,V visible; xb reads done -> xb writable

        // ---- T14 issue here (stage regs live only B1 -> pre-B3) ----
        float4 s0a, s0b, s1a, s1b;
        if (hn) {
            const float* xs = x + (size_t)(b + 1) * NWIN * CDIM;
            const float* sp0 = xs + (size_t)r0 * CDIM + gc;
            s0a = *reinterpret_cast<const float4*>(sp0);
            s0b = *reinterpret_cast<const float4*>(sp0 + 4);
            int row1 = r0 + 32;
            if (row1 < 49) {
                const float* sp1 = xs + (size_t)row1 * CDIM + gc;
                s1a = *reinterpret_cast<const float4*>(sp1);
                s1b = *reinterpret_cast<const float4*>(sp1 + 4);
            }
        }

        // ---- hoist K,Q,V fragment reads (P overlays Q|K; O will overlay V) ----
        half8 kf[2], qf[4], vf0, vf1;
#pragma unroll
        for (int kt = 0; kt < 2; ++kt)
            kf[kt] = *reinterpret_cast<const half8*>(&Kh[(16 * (2 * c + kt) + lo) * QK_STR + hi * 8]);
#pragma unroll
        for (int t = 0; t < 4; ++t)
            qf[t] = *reinterpret_cast<const half8*>(&Qh[(16 * t + lo) * QK_STR + hi * 8]);
        {
            const _Float16* vp = &Vh[(16 * c + lo) * VT_STR + hi * 8];
            vf0 = *reinterpret_cast<const half8*>(vp);
            vf1 = *reinterpret_cast<const half8*>(vp + 32);
        }
        __syncthreads();  // B2: Q/K/V reads done -> P region writable; O region armed

        // ---- S^T slice, exp2 (bases folded; raw v_exp_f32), P stores, sums in pad ----
#pragma unroll
        for (int tnq = 0; tnq < 4; ++tnq) {
            int q = 16 * tnq + lo;
            int qc = (q < 49) ? q : 48;   // bias gather address must stay in-table
            const _Float16* bb = ws + WS_BIAS + ((size_t)h * 49 + qc) * 64 + 32 * c + 4 * hi;
            float sum = 0.f;
#pragma unroll
            for (int kt = 0; kt < 2; ++kt) {
                f32x4 s = __builtin_amdgcn_mfma_f32_16x16x32_f16(kf[kt], qf[tnq], zf, 0, 0, 0);
                half4v bt = *reinterpret_cast<const half4v*>(bb + kt * 16);
                float p0 = __builtin_amdgcn_exp2f(s[0] + (float)bt[0]);
                float p1 = __builtin_amdgcn_exp2f(s[1] + (float)bt[1]);
                float p2 = __builtin_amdgcn_exp2f(s[2] + (float)bt[2]);
                float p3 = __builtin_amdgcn_exp2f(s[3] + (float)bt[3]);
                sum += p0 + p1 + p2 + p3;
                *reinterpret_cast<half4v*>(&Ph[q * P_STR + 32 * c + 16 * kt + 4 * hi]) =
                    pk4(p0, p1, p2, p3);
            }
            sum += __shfl_xor(sum, 16);
            sum += __shfl_xor(sum, 32);
            if (hi == 0)
                *reinterpret_cast<float*>(&Ph[q * P_STR + 64 + 2 * c]) = sum;
        }

        // ---- T14 write-late: next-window x regs -> xb (reads done at B1;
        //      visibility to next GEMM1 ordered by B3+B4+B5) ----
        if (hn) {
            *reinterpret_cast<half8*>(&xb[r0 * XL_STR + gc]) = pk8(s0a, s0b);
            int row1 = r0 + 32;
            if (row1 < 49)
                *reinterpret_cast<half8*>(&xb[row1 * XL_STR + gc]) = pk8(s1a, s1b);
        }
        __syncthreads();  // B3: P + sums visible; all V reads long done

        // ---- PV: pure-reg V-frags; normalized O -> Ob (overlays V region) ----
#pragma unroll
        for (int tnq = 0; tnq < 4; ++tnq) {
            int q = 16 * tnq + lo;
            half8 pf0 = *reinterpret_cast<const half8*>(&Ph[q * P_STR + hi * 8]);
            half8 pf1 = *reinterpret_cast<const half8*>(&Ph[q * P_STR + 32 + hi * 8]);
            f32x4 o = __builtin_amdgcn_mfma_f32_16x16x32_f16(vf0, pf0, zf, 0, 0, 0);
            o = __builtin_amdgcn_mfma_f32_16x16x32_f16(vf1, pf1, o, 0, 0, 0);
            float2 s2 = *reinterpret_cast<const float2*>(&Ph[q * P_STR + 64]);
            float invl = 1.0f / (s2.x + s2.y);
            *reinterpret_cast<half4v*>(&Ob[q * XL_STR + 32 * h + 16 * c + 4 * hi]) =
                pk4(o[0] * invl, o[1] * invl, o[2] * invl, o[3] * invl);
        }
        __syncthreads();  // B4: O complete; orders P-reads < next GEMM1 Q/K stores

        // ---- GEMM3: one 32x32 output tile per wave via mfma_f32_32x32x16_f16 ----
        {
            const _Float16* wb3 = ws + WS_WPROJ + (size_t)(32 * ct + cl) * CDIM + kh * 8;
            half8 bfr[8];
#pragma unroll
            for (int kk = 0; kk < 8; ++kk)
                bfr[kk] = *reinterpret_cast<const half8*>(wb3 + kk * 16);

            f32x16 g;
#pragma unroll
            for (int r = 0; r < 16; ++r) g[r] = bpe3;

            const _Float16* oa = &Ob[(32 * rt + cl) * XL_STR + kh * 8];
#pragma unroll
            for (int kk = 0; kk < 8; ++kk) {
                half8 af = *reinterpret_cast<const half8*>(oa + kk * 16);
                g = __builtin_amdgcn_mfma_f32_32x32x16_f16(af, bfr[kk], g, 0, 0, 0);
            }
#pragma unroll
            for (int r = 0; r < 16; ++r) {
                int row = 32 * rt + (r & 3) + 8 * (r >> 2) + 4 * kh;
                if (row < 49)
                    out[((size_t)b * NWIN + row) * CDIM + 32 * ct + cl] = g[r];
            }
        }
        __syncthreads();  // B5: O reads done -> V region writable by next GEMM1
    }
}

extern "C" void kernel_launch(void* const* d_in, const int* in_sizes, int n_in,
                              void* d_out, int out_size, void* d_ws, size_t ws_size,
                              hipStream_t stream) {
    const float* x          = (const float*)d_in[0];
    // d_in[1] = q_global: unused by the reference
    const float* w_qkv      = (const float*)d_in[2];
    const float* b_qkv      = (const float*)d_in[3];
    const float* w_proj     = (const float*)d_in[4];
    const float* b_proj     = (const float*)d_in[5];
    const float* bias_table = (const float*)d_in[6];
    const int*   rel_index  = (const int*)d_in[7];

    _Float16* ws = (_Float16*)d_ws;

    prepack<<<(WS_TOTAL + 255) / 256, 256, 0, stream>>>(w_qkv, b_qkv, w_proj,
                                                        bias_table, rel_index, ws);

    const int nwin = in_sizes[0] / (NWIN * CDIM);   // 16384
    const int wpb = 16;
    const int nblk = (nwin + wpb - 1) / wpb;        // 1024

    lwa_fused<<<nblk, 512, 0, stream>>>(x, ws, b_proj, (float*)d_out,
                                        nwin, wpb);
}

// Round 19
// 296.479 us; speedup vs baseline: 1.9113x; 1.9113x over previous
//
#include <hip/hip_runtime.h>

#define NWIN 49
#define CDIM 128
#define SCALEQ 0.17677669529663687f
#define LOG2E  1.4426950408889634f

typedef _Float16 half8 __attribute__((ext_vector_type(8)));
typedef _Float16 half4v __attribute__((ext_vector_type(4)));
typedef float f32x4 __attribute__((ext_vector_type(4)));
typedef float f32x16 __attribute__((ext_vector_type(16)));

// ---- d_ws f16 layout (element offsets) ----
#define WS_WQKV  0        // [384][128] f16, q-rows pre-scaled by SCALEQ*LOG2E
#define WS_WPROJ 49152    // [128][128] f16
#define WS_BQKV  65536    // [384] f16 (q part pre-scaled by SCALEQ*LOG2E)
#define WS_BIAS  65920    // [4][49][64] f16: bias*LOG2E, key>=49 -> -1.44e4
#define WS_TOTAL 78464    // halves

// ---- LDS strides (halves) ----
#define XL_STR 136        // x / O tile row stride (272 B)
#define QK_STR 40         // Q,K row stride (80 B)
#define P_STR  72         // P row stride (144 B); cols 64..67 hold f32 partial sums
#define VT_STR 72         // V[d][token] row stride (144 B; 64 tokens + pad)

#define XBUF_H  (49 * XL_STR)          // 6664 halves: x only
#define K_OFF_H (64 * QK_STR)          // 2560: K after Q
#define HEAD_H  (2 * K_OFF_H)          // 5120 per head (P overlay 64*72=4608 <= 5120)
#define VBUF_H  (32 * VT_STR)          // 2304 per head: V[d][token]
#define VREG_H  (4 * VBUF_H)           // 9216: all-V region; O (64x136=8704) overlays it
#define SMEM_H  (XBUF_H + 4 * HEAD_H + VREG_H) // 36360 halves = 72720 B -> 2 blocks/CU

static __device__ __forceinline__ half4v pk4(float a, float b, float c, float d) {
    auto p0 = __builtin_amdgcn_cvt_pkrtz(a, b);
    auto p1 = __builtin_amdgcn_cvt_pkrtz(c, d);
    int2 r = { __builtin_bit_cast(int, p0), __builtin_bit_cast(int, p1) };
    return __builtin_bit_cast(half4v, r);
}
static __device__ __forceinline__ half8 pk8(float4 u0, float4 u1) {
    auto p0 = __builtin_amdgcn_cvt_pkrtz(u0.x, u0.y);
    auto p1 = __builtin_amdgcn_cvt_pkrtz(u0.z, u0.w);
    auto p2 = __builtin_amdgcn_cvt_pkrtz(u1.x, u1.y);
    auto p3 = __builtin_amdgcn_cvt_pkrtz(u1.z, u1.w);
    int4 r = { __builtin_bit_cast(int, p0), __builtin_bit_cast(int, p1),
               __builtin_bit_cast(int, p2), __builtin_bit_cast(int, p3) };
    return __builtin_bit_cast(half8, r);
}

__global__ __launch_bounds__(256)
void prepack(const float* __restrict__ w_qkv, const float* __restrict__ b_qkv,
             const float* __restrict__ w_proj, const float* __restrict__ bias_table,
             const int* __restrict__ rel_index, _Float16* __restrict__ ws)
{
    int i = blockIdx.x * 256 + threadIdx.x;
    if (i < 49152) {
        float v = w_qkv[i];
        if (i < 16384) v *= SCALEQ * LOG2E;  // q rows: fold softmax base-2
        ws[WS_WQKV + i] = (_Float16)v;
    } else if (i < 65536) {
        ws[i] = (_Float16)w_proj[i - 49152];
    } else if (i < 65920) {
        int n = i - 65536;
        float v = b_qkv[n];
        if (n < 128) v *= SCALEQ * LOG2E;
        ws[WS_BQKV + n] = (_Float16)v;
    } else if (i < WS_TOTAL) {
        int t = i - 65920;
        int h = t / 3136;                    // 49*64
        int r = t - h * 3136;
        int q = r >> 6;
        int key = r & 63;
        float v = (key < 49) ? bias_table[(size_t)rel_index[q * 49 + key] * 4 + h] * LOG2E
                             : -1.44e4f;     // exp2 -> 0
        ws[WS_BIAS + t] = (_Float16)v;
    }
}

// 512 threads = 8 waves. r17 structure (299us best) with ONE change: T14's
// global loads issue AFTER B1 (not loop-top), write before B3. Stage regs no
// longer co-live with GEMM1's hoisted 12-frag weight cache -> removes r17's
// +12MB WRITE spill. (r18's GEMM1 32x32 retile REVERTED: per-iteration weight
// streaming in a rolled loop exposed L1 latency — 4th instance of that trap.)
__global__ __launch_bounds__(512)
void lwa_fused(const float* __restrict__ x, const _Float16* __restrict__ ws,
               const float* __restrict__ b_proj, float* __restrict__ out,
               int nwin_total, int wpb)
{
    __shared__ __align__(16) _Float16 smem[SMEM_H];

    const int tid  = threadIdx.x;
    const int w    = tid >> 6;
    const int h    = w >> 1;
    const int c    = w & 1;
    const int lane = tid & 63;
    const int lo   = lane & 15;
    const int hi   = lane >> 4;
    const int ncol = 32 * h + 16 * c + lo;

    _Float16* const xb = smem;                       // x (49 x 136)
    _Float16* const Qh = smem + XBUF_H + h * HEAD_H; // 64 x 32, stride 40
    _Float16* const Kh = Qh + K_OFF_H;               // 64 x 32, stride 40
    _Float16* const Ph = Qh;                         // overlay: 64 x 64 (+sums pad), stride 72
    _Float16* const Vh = smem + XBUF_H + 4 * HEAD_H + h * VBUF_H; // V[d][token] 32 x 72
    _Float16* const Ob = smem + XBUF_H + 4 * HEAD_H; // O (64 x 136) overlays V region

    const f32x4 zf = {0.f, 0.f, 0.f, 0.f};

    // GEMM3 32x32-tile mapping: wave (rt, ct), lane (cl, kh)
    const int rt = w >> 2;
    const int ct = w & 3;
    const int cl = lane & 31;
    const int kh = lane >> 5;
    const float bpe3 = b_proj[32 * ct + cl];

    const int r0 = tid >> 4;            // 0..31
    const int gc = (tid & 15) * 8;

    int b0 = blockIdx.x * wpb;
    int b1 = b0 + wpb; if (b1 > nwin_total) b1 = nwin_total;

    // ---------- prologue: stage x[b0] ----------
    {
        const float* xs = x + (size_t)b0 * NWIN * CDIM;
#pragma unroll
        for (int p = 0; p < 2; ++p) {
            int row = r0 + p * 32;
            if (row < 49) {
                const float* sp = xs + (size_t)row * CDIM + gc;
                float4 u0 = *reinterpret_cast<const float4*>(sp);
                float4 u1 = *reinterpret_cast<const float4*>(sp + 4);
                *reinterpret_cast<half8*>(&xb[row * XL_STR + gc]) = pk8(u0, u1);
            }
        }
    }
    __syncthreads();   // B0 (prologue only): x visible

    for (int b = b0; b < b1; ++b) {
        const bool hn = (b + 1 < b1);

        // ---- GEMM1 weight preload (hoisted ONCE, reused x4 — never stream) ----
        half8 wf0[4], wf1[4], wf2[4];
        {
            const _Float16* wp0 = ws + WS_WQKV + (size_t)ncol * CDIM + hi * 8;
            const _Float16* wp1 = wp0 + (size_t)CDIM * CDIM;
            const _Float16* wp2 = wp1 + (size_t)CDIM * CDIM;
#pragma unroll
            for (int kk = 0; kk < 4; ++kk) {
                wf0[kk] = *reinterpret_cast<const half8*>(wp0 + kk * 32);
                wf1[kk] = *reinterpret_cast<const half8*>(wp1 + kk * 32);
                wf2[kk] = *reinterpret_cast<const half8*>(wp2 + kk * 32);
            }
        }
        // Q/K bias per-j (outcol = 32h+16c+4hi+j for swapped output tiles)
        half4v bqq = *reinterpret_cast<const half4v*>(ws + WS_BQKV + 32 * h + 16 * c + 4 * hi);
        half4v bqk = *reinterpret_cast<const half4v*>(ws + WS_BQKV + CDIM + 32 * h + 16 * c + 4 * hi);
        float bq2 = (float)ws[WS_BQKV + 2 * CDIM + ncol];

        // ---- GEMM1: x A-frags read once from LDS ----
        //   Q,K: mfma(wf, a) -> D[outcol][token] -> packed half4v store (r15).
        //   V:   mfma(a, wf2) -> D[token][vcol] -> packed V^T write (r7 layout).
#pragma unroll 1
        for (int tm = 0; tm < 4; ++tm) {
            int ar = 16 * tm + lo; if (ar > 48) ar = 48;
            const _Float16* ap = &xb[ar * XL_STR + hi * 8];
            half8 a0 = *reinterpret_cast<const half8*>(ap);
            half8 a1 = *reinterpret_cast<const half8*>(ap + 32);
            half8 a2 = *reinterpret_cast<const half8*>(ap + 64);
            half8 a3 = *reinterpret_cast<const half8*>(ap + 96);

            f32x4 aq; aq[0] = (float)bqq[0]; aq[1] = (float)bqq[1];
                      aq[2] = (float)bqq[2]; aq[3] = (float)bqq[3];
            aq = __builtin_amdgcn_mfma_f32_16x16x32_f16(wf0[0], a0, aq, 0, 0, 0);
            aq = __builtin_amdgcn_mfma_f32_16x16x32_f16(wf0[1], a1, aq, 0, 0, 0);
            aq = __builtin_amdgcn_mfma_f32_16x16x32_f16(wf0[2], a2, aq, 0, 0, 0);
            aq = __builtin_amdgcn_mfma_f32_16x16x32_f16(wf0[3], a3, aq, 0, 0, 0);

            f32x4 ak; ak[0] = (float)bqk[0]; ak[1] = (float)bqk[1];
                      ak[2] = (float)bqk[2]; ak[3] = (float)bqk[3];
            ak = __builtin_amdgcn_mfma_f32_16x16x32_f16(wf1[0], a0, ak, 0, 0, 0);
            ak = __builtin_amdgcn_mfma_f32_16x16x32_f16(wf1[1], a1, ak, 0, 0, 0);
            ak = __builtin_amdgcn_mfma_f32_16x16x32_f16(wf1[2], a2, ak, 0, 0, 0);
            ak = __builtin_amdgcn_mfma_f32_16x16x32_f16(wf1[3], a3, ak, 0, 0, 0);

            f32x4 av; av[0] = bq2; av[1] = bq2; av[2] = bq2; av[3] = bq2;
            av = __builtin_amdgcn_mfma_f32_16x16x32_f16(a0, wf2[0], av, 0, 0, 0);
            av = __builtin_amdgcn_mfma_f32_16x16x32_f16(a1, wf2[1], av, 0, 0, 0);
            av = __builtin_amdgcn_mfma_f32_16x16x32_f16(a2, wf2[2], av, 0, 0, 0);
            av = __builtin_amdgcn_mfma_f32_16x16x32_f16(a3, wf2[3], av, 0, 0, 0);

            // Q,K packed epilogue: token 16tm+lo (pad tokens 49..63 hold dup of 48)
            *reinterpret_cast<half4v*>(&Qh[(16 * tm + lo) * QK_STR + 16 * c + 4 * hi]) =
                pk4(aq[0], aq[1], aq[2], aq[3]);
            *reinterpret_cast<half4v*>(&Kh[(16 * tm + lo) * QK_STR + 16 * c + 4 * hi]) =
                pk4(ak[0], ak[1], ak[2], ak[3]);
            // V packed write into V[d][token]: d=16c+lo, tokens 16tm+4hi..+3
            *reinterpret_cast<half4v*>(&Vh[(16 * c + lo) * VT_STR + 16 * tm + 4 * hi]) =
                pk4(av[0], av[1], av[2], av[3]);
        }
        __syncthreads();  // B1: Q,K,V visible; xb reads done -> xb writable

        // ---- T14 issue here (post-B1): stage regs never co-live with GEMM1's
        //      weight cache; latency hides under hoists + B2 + softmax ----
        float4 s0a, s0b, s1a, s1b;
        if (hn) {
            const float* xs = x + (size_t)(b + 1) * NWIN * CDIM;
            const float* sp0 = xs + (size_t)r0 * CDIM + gc;
            s0a = *reinterpret_cast<const float4*>(sp0);
            s0b = *reinterpret_cast<const float4*>(sp0 + 4);
            int row1 = r0 + 32;
            if (row1 < 49) {
                const float* sp1 = xs + (size_t)row1 * CDIM + gc;
                s1a = *reinterpret_cast<const float4*>(sp1);
                s1b = *reinterpret_cast<const float4*>(sp1 + 4);
            }
        }

        // ---- hoist K,Q,V fragment reads (P overlays Q|K; O will overlay V) ----
        half8 kf[2], qf[4], vf0, vf1;
#pragma unroll
        for (int kt = 0; kt < 2; ++kt)
            kf[kt] = *reinterpret_cast<const half8*>(&Kh[(16 * (2 * c + kt) + lo) * QK_STR + hi * 8]);
#pragma unroll
        for (int t = 0; t < 4; ++t)
            qf[t] = *reinterpret_cast<const half8*>(&Qh[(16 * t + lo) * QK_STR + hi * 8]);
        {
            const _Float16* vp = &Vh[(16 * c + lo) * VT_STR + hi * 8];
            vf0 = *reinterpret_cast<const half8*>(vp);
            vf1 = *reinterpret_cast<const half8*>(vp + 32);
        }
        __syncthreads();  // B2: Q/K/V reads done -> P region writable; O region armed

        // ---- S^T slice, exp2 (bases folded; raw v_exp_f32), P stores, sums in pad ----
#pragma unroll
        for (int tnq = 0; tnq < 4; ++tnq) {
            int q = 16 * tnq + lo;
            int qc = (q < 49) ? q : 48;   // bias gather address must stay in-table
            const _Float16* bb = ws + WS_BIAS + ((size_t)h * 49 + qc) * 64 + 32 * c + 4 * hi;
            float sum = 0.f;
#pragma unroll
            for (int kt = 0; kt < 2; ++kt) {
                f32x4 s = __builtin_amdgcn_mfma_f32_16x16x32_f16(kf[kt], qf[tnq], zf, 0, 0, 0);
                half4v bt = *reinterpret_cast<const half4v*>(bb + kt * 16);
                float p0 = __builtin_amdgcn_exp2f(s[0] + (float)bt[0]);
                float p1 = __builtin_amdgcn_exp2f(s[1] + (float)bt[1]);
                float p2 = __builtin_amdgcn_exp2f(s[2] + (float)bt[2]);
                float p3 = __builtin_amdgcn_exp2f(s[3] + (float)bt[3]);
                sum += p0 + p1 + p2 + p3;
                *reinterpret_cast<half4v*>(&Ph[q * P_STR + 32 * c + 16 * kt + 4 * hi]) =
                    pk4(p0, p1, p2, p3);
            }
            sum += __shfl_xor(sum, 16);
            sum += __shfl_xor(sum, 32);
            if (hi == 0)
                *reinterpret_cast<float*>(&Ph[q * P_STR + 64 + 2 * c]) = sum;
        }

        // ---- T14 write-late: next-window x regs -> xb (reads done at B1;
        //      visibility to next GEMM1 ordered by B3+B4+B5) ----
        if (hn) {
            *reinterpret_cast<half8*>(&xb[r0 * XL_STR + gc]) = pk8(s0a, s0b);
            int row1 = r0 + 32;
            if (row1 < 49)
                *reinterpret_cast<half8*>(&xb[row1 * XL_STR + gc]) = pk8(s1a, s1b);
        }
        __syncthreads();  // B3: P + sums visible; all V reads long done

        // ---- PV: pure-reg V-frags; normalized O -> Ob (overlays V region) ----
#pragma unroll
        for (int tnq = 0; tnq < 4; ++tnq) {
            int q = 16 * tnq + lo;
            half8 pf0 = *reinterpret_cast<const half8*>(&Ph[q * P_STR + hi * 8]);
            half8 pf1 = *reinterpret_cast<const half8*>(&Ph[q * P_STR + 32 + hi * 8]);
            f32x4 o = __builtin_amdgcn_mfma_f32_16x16x32_f16(vf0, pf0, zf, 0, 0, 0);
            o = __builtin_amdgcn_mfma_f32_16x16x32_f16(vf1, pf1, o, 0, 0, 0);
            float2 s2 = *reinterpret_cast<const float2*>(&Ph[q * P_STR + 64]);
            float invl = 1.0f / (s2.x + s2.y);
            *reinterpret_cast<half4v*>(&Ob[q * XL_STR + 32 * h + 16 * c + 4 * hi]) =
                pk4(o[0] * invl, o[1] * invl, o[2] * invl, o[3] * invl);
        }
        __syncthreads();  // B4: O complete; orders P-reads < next GEMM1 Q/K stores

        // ---- GEMM3: one 32x32 output tile per wave via mfma_f32_32x32x16_f16 ----
        {
            const _Float16* wb3 = ws + WS_WPROJ + (size_t)(32 * ct + cl) * CDIM + kh * 8;
            half8 bfr[8];
#pragma unroll
            for (int kk = 0; kk < 8; ++kk)
                bfr[kk] = *reinterpret_cast<const half8*>(wb3 + kk * 16);

            f32x16 g;
#pragma unroll
            for (int r = 0; r < 16; ++r) g[r] = bpe3;

            const _Float16* oa = &Ob[(32 * rt + cl) * XL_STR + kh * 8];
#pragma unroll
            for (int kk = 0; kk < 8; ++kk) {
                half8 af = *reinterpret_cast<const half8*>(oa + kk * 16);
                g = __builtin_amdgcn_mfma_f32_32x32x16_f16(af, bfr[kk], g, 0, 0, 0);
            }
#pragma unroll
            for (int r = 0; r < 16; ++r) {
                int row = 32 * rt + (r & 3) + 8 * (r >> 2) + 4 * kh;
                if (row < 49)
                    out[((size_t)b * NWIN + row) * CDIM + 32 * ct + cl] = g[r];
            }
        }
        __syncthreads();  // B5: O reads done -> V region writable by next GEMM1
    }
}

extern "C" void kernel_launch(void* const* d_in, const int* in_sizes, int n_in,
                              void* d_out, int out_size, void* d_ws, size_t ws_size,
                              hipStream_t stream) {
    const float* x          = (const float*)d_in[0];
    // d_in[1] = q_global: unused by the reference
    const float* w_qkv      = (const float*)d_in[2];
    const float* b_qkv      = (const float*)d_in[3];
    const float* w_proj     = (const float*)d_in[4];
    const float* b_proj     = (const float*)d_in[5];
    const float* bias_table = (const float*)d_in[6];
    const int*   rel_index  = (const int*)d_in[7];

    _Float16* ws = (_Float16*)d_ws;

    prepack<<<(WS_TOTAL + 255) / 256, 256, 0, stream>>>(w_qkv, b_qkv, w_proj,
                                                        bias_table, rel_index, ws);

    const int nwin = in_sizes[0] / (NWIN * CDIM);   // 16384
    const int wpb = 16;
    const int nblk = (nwin + wpb - 1) / wpb;        // 1024

    lwa_fused<<<nblk, 512, 0, stream>>>(x, ws, b_proj, (float*)d_out,
                                        nwin, wpb);
}